// Round 9
// baseline (147.730 us; speedup 1.0000x reference)
//
#include <hip/hip_runtime.h>

#define THREADS 256
#define NPAIR 1048576            // 2097152 rows / 2 rows per thread
#define BLOCKS (NPAIR / THREADS) // 4096
#define DT 0.005f
#define INV_HUBER 200.0f         // 1/0.005

#define NELEM 6291456.0          // 128*16384*3
#define CNT16 391296.0           // 128*1019*3
#define CNT32 194688.0           // 128*507*3

__device__ __forceinline__ float rcpf(float x) {
    return __builtin_amdgcn_rcpf(x);
}

// acos via A&S 4.4.46 7-term poly: |err| < 2e-8 rad (exact at f32)
__device__ __forceinline__ float acos_poly(float x) {
    float ax = fabsf(x);
    float p = fmaf(ax, -0.0012624911f, 0.0066700901f);
    p = fmaf(ax, p, -0.0170881256f);
    p = fmaf(ax, p, 0.0308918810f);
    p = fmaf(ax, p, -0.0501743046f);
    p = fmaf(ax, p, 0.0889789874f);
    p = fmaf(ax, p, -0.2145988016f);
    p = fmaf(ax, p, 1.5707963050f);
    float r = sqrtf(fmaxf(1.0f - ax, 0.0f)) * p;
    return x < 0.0f ? 3.14159265358979f - r : r;
}

// Rodrigues, small-angle (|phi| <= ~0.04): Taylor st/ct
__device__ __forceinline__ void so3_exp_small(float x, float y, float z, float R[9]) {
    float a2 = x * x + y * y + z * z;
    float st = 1.0f - a2 * (1.0f / 6.0f) * (1.0f - a2 * (1.0f / 20.0f));
    float ct = 0.5f - a2 * (1.0f / 24.0f) * (1.0f - a2 * (1.0f / 30.0f));
    R[0] = 1.0f + ct * (x * x - a2);
    R[1] = ct * (x * y) - st * z;
    R[2] = ct * (x * z) + st * y;
    R[3] = ct * (x * y) + st * z;
    R[4] = 1.0f + ct * (y * y - a2);
    R[5] = ct * (y * z) - st * x;
    R[6] = ct * (x * z) - st * y;
    R[7] = ct * (y * z) + st * x;
    R[8] = 1.0f + ct * (z * z - a2);
}

// Rodrigues, full range — hardware trig
__device__ __forceinline__ void so3_exp_full(float x, float y, float z, float R[9]) {
    float a2 = x * x + y * y + z * z;
    bool sm = a2 < 1e-12f;
    float a2s = sm ? 1.0f : a2;
    float a = sqrtf(a2s);
    float s = __sinf(a);
    float c = __cosf(a);
    float st = sm ? (1.0f - a2 * (1.0f / 6.0f)) : (s * rcpf(a));
    float ct = sm ? (0.5f - a2 * (1.0f / 24.0f)) : ((1.0f - c) * rcpf(a2s));
    R[0] = 1.0f + ct * (x * x - a2);
    R[1] = ct * (x * y) - st * z;
    R[2] = ct * (x * z) + st * y;
    R[3] = ct * (x * y) + st * z;
    R[4] = 1.0f + ct * (y * y - a2);
    R[5] = ct * (y * z) - st * x;
    R[6] = ct * (x * z) - st * y;
    R[7] = ct * (y * z) + st * x;
    R[8] = 1.0f + ct * (z * z - a2);
}

__device__ __forceinline__ void mm3(const float A[9], const float B[9], float C[9]) {
#pragma unroll
    for (int i = 0; i < 3; ++i) {
        float a0 = A[3 * i], a1 = A[3 * i + 1], a2 = A[3 * i + 2];
        C[3 * i + 0] = a0 * B[0] + a1 * B[3] + a2 * B[6];
        C[3 * i + 1] = a0 * B[1] + a1 * B[4] + a2 * B[7];
        C[3 * i + 2] = a0 * B[2] + a1 * B[5] + a2 * B[8];
    }
}

__device__ __forceinline__ float huber_bmtm(const float A[9], const float B[9]) {
    float tr = 0.f, w0 = 0.f, w1 = 0.f, w2 = 0.f;
#pragma unroll
    for (int k = 0; k < 3; ++k) {
        float a0 = A[3 * k], a1 = A[3 * k + 1], a2v = A[3 * k + 2];
        float b0 = B[3 * k], b1 = B[3 * k + 1], b2v = B[3 * k + 2];
        tr += a0 * b0 + a1 * b1 + a2v * b2v;
        w0 += a2v * b1 - a1 * b2v;
        w1 += a0 * b2v - a2v * b0;
        w2 += a1 * b0 - a0 * b1;
    }
    float cs = 0.5f * (tr - 1.0f);
    cs = fminf(fmaxf(cs, -1.0f + 1e-6f), 1.0f - 1e-6f);
    float ang = acos_poly(cs);
    float sn = sqrtf(fmaxf(1.0f - cs * cs, 0.0f));
    float fac = ang * 0.5f * rcpf(sn);
    float h = 0.0f, r;
    r = fabsf(fac * w0 * INV_HUBER); h += (r < 1.0f) ? 0.5f * r * r : (r - 0.5f);
    r = fabsf(fac * w1 * INV_HUBER); h += (r < 1.0f) ? 0.5f * r * r : (r - 0.5f);
    r = fabsf(fac * w2 * INV_HUBER); h += (r < 1.0f) ? 0.5f * r * r : (r - 0.5f);
    return h;
}

__device__ __forceinline__ float gnll2(float2 h, float2 g, float2 m, float2 s) {
    float p = 0.f;
#pragma unroll
    for (int k = 0; k < 2; ++k) {
        float hv = (&h.x)[k], gv = (&g.x)[k], mv = (&m.x)[k], sv = (&s.x)[k];
        float v = fmaxf(sv * sv, 1e-6f);
        float d = gv - hv - mv;
        float rv = rcpf(v);
        rv = rv * (2.0f - v * rv);
        p += __logf(v) + d * d * rv;
    }
    return p;
}

__global__ __launch_bounds__(THREADS) void dg_loss_kernel(
    const float* __restrict__ w_hat, const float* __restrict__ dw16,
    const float* __restrict__ w_gt, const float* __restrict__ w_mean,
    const float* __restrict__ w_std, double* __restrict__ partial)
{
    const int tid = threadIdx.x;
    const int t = blockIdx.x * THREADS + tid;           // pair-row index, 0..NPAIR-1
    const int lane = tid & 63;

    // ---- all loads issued up front, fully independent (no LDS, no barrier) ----
    const float2* h2 = (const float2*)w_hat;
    const float2* g2 = (const float2*)w_gt;
    const float2* m2 = (const float2*)w_mean;
    const float2* s2 = (const float2*)w_std;
    const size_t p3 = (size_t)t * 3;
    float2 Ha = h2[p3], Hb = h2[p3 + 1], Hc = h2[p3 + 2];
    float2 Ga = g2[p3], Gb = g2[p3 + 1], Gc = g2[p3 + 2];
    float2 Ma = m2[p3], Mb = m2[p3 + 1], Mc = m2[p3 + 2];
    float2 Sa = s2[p3], Sb = s2[p3 + 1], Sc = s2[p3 + 2];
    const int b = t >> 3;                               // global 16-block index
    float4 q4 = ((const float4*)dw16)[(size_t)b * 12];  // dw16 row 16*b

    // ---- gaussian NLL on this thread's 6 elements ----
    double lg = 0.5 * (double)(gnll2(Ha, Ga, Ma, Sa) +
                               gnll2(Hb, Gb, Mb, Sb) +
                               gnll2(Hc, Gc, Mc, Sc));

    // ---- in-lane: 2 exps + 1 mm3 (pairwise level 1) ----
    float E0[9], E1[9], P[9];
    so3_exp_small(DT * Ha.x, DT * Ha.y, DT * Hb.x, E0);     // row 2t
    so3_exp_small(DT * Hb.y, DT * Hc.x, DT * Hc.y, E1);     // row 2t+1
    mm3(E0, E1, P);

    // ---- butterfly over 8-lane groups: strides 1,2,4 -> ordered 16-row product ----
#pragma unroll
    for (int s = 1; s <= 4; s <<= 1) {
        float Nb[9];
#pragma unroll
        for (int e = 0; e < 9; ++e) Nb[e] = __shfl_xor(P[e], s);
        const bool rt = (lane & s) != 0;
        float A[9], B[9], T[9];
#pragma unroll
        for (int e = 0; e < 9; ++e) { A[e] = rt ? Nb[e] : P[e]; B[e] = rt ? P[e] : Nb[e]; }
        mm3(A, B, T);
#pragma unroll
        for (int e = 0; e < 9; ++e) P[e] = T[e];
    }

    // Q16 = exp(dw16 row) — every lane, branch-free
    float Q[9];
    so3_exp_full(q4.x, q4.y, q4.z, Q);

    // ---- merged 16/32-level huber: one wave-wide call ----
    float Pn[9], Qn[9];
#pragma unroll
    for (int e = 0; e < 9; ++e) {
        Pn[e] = __shfl_xor(P[e], 8);                    // partner 16-group
        Qn[e] = __shfl_xor(Q[e], 8);
    }
    float T1[9], T2[9];
    mm3(P, Pn, T1);                                     // valid on even-group lanes
    mm3(Q, Qn, T2);
    const bool role16 = (lane & 7) == 0;                // one lane per 16-block
    const bool role32 = (lane & 15) == 1;               // one lane per 32-block (even group)
    float A[9], B[9];
#pragma unroll
    for (int e = 0; e < 9; ++e) {
        A[e] = role16 ? P[e] : T1[e];
        B[e] = role16 ? Q[e] : T2[e];
    }
    float hub = huber_bmtm(A, B);
    double lh16 = 0.0, lh32 = 0.0;
    if (role16 && ((b & 1023) >= 5)) lh16 = (double)hub;    // skip N0=5 16-blocks/traj
    const int c = t >> 4;                                   // global 32-block index
    if (role32 && ((c & 511) >= 5)) lh32 = (double)hub;     // skip N0=5 32-blocks/traj

    // ---- block reduction: pre-scaled single double, plain store (no atomics) ----
    double part = lg * (1.0 / NELEM) + lh16 * (25.0 / CNT16) + lh32 * (6.25 / CNT32);
    __shared__ double s_p[4];
#pragma unroll
    for (int off = 32; off > 0; off >>= 1)
        part += __shfl_down(part, off);
    const int wv = tid >> 6;
    if (lane == 0) s_p[wv] = part;
    __syncthreads();
    if (tid == 0)
        partial[blockIdx.x] = s_p[0] + s_p[1] + s_p[2] + s_p[3];
}

__global__ __launch_bounds__(THREADS) void finalize_kernel(
    const double* __restrict__ partial, float* __restrict__ out)
{
    double s = 0.0;
#pragma unroll
    for (int i = 0; i < BLOCKS / THREADS; ++i)          // 16 strided loads each
        s += partial[i * THREADS + threadIdx.x];
    __shared__ double s_p[4];
#pragma unroll
    for (int off = 32; off > 0; off >>= 1)
        s += __shfl_down(s, off);
    const int lane = threadIdx.x & 63, wv = threadIdx.x >> 6;
    if (lane == 0) s_p[wv] = s;
    __syncthreads();
    if (threadIdx.x == 0)
        out[0] = (float)(s_p[0] + s_p[1] + s_p[2] + s_p[3]);
}

extern "C" void kernel_launch(void* const* d_in, const int* in_sizes, int n_in,
                              void* d_out, int out_size, void* d_ws, size_t ws_size,
                              hipStream_t stream) {
    const float* w_hat = (const float*)d_in[0];
    const float* dw16 = (const float*)d_in[1];
    const float* w_gt = (const float*)d_in[2];
    const float* w_mean = (const float*)d_in[3];
    const float* w_std = (const float*)d_in[4];
    float* out = (float*)d_out;
    double* partial = (double*)d_ws;                   // BLOCKS doubles = 32 KB

    dg_loss_kernel<<<BLOCKS, THREADS, 0, stream>>>(
        w_hat, dw16, w_gt, w_mean, w_std, partial);
    finalize_kernel<<<1, THREADS, 0, stream>>>(partial, out);
}